// Round 8
// baseline (360.055 us; speedup 1.0000x reference)
//
#include <hip/hip_runtime.h>
#include <hip/hip_bf16.h>
#include <math.h>

#define B_SZ 4
#define LSEQ 2048
#define DM 1024
#define DI 2048
#define DH 1024
#define DS 16
#define DTR 64
#define RTOT 96
#define MROWS (B_SZ * LSEQ) /* 8192 */

// scan chunking
#define NCH 32
#define CHUNK 64 /* LSEQ / NCH */

// delta split-bf16 GEMM K (hi|lo|hi vs Whi|Whi|Wlo)
#define KD 192
#define KDP 200 /* padded LDS row (shorts): 400B = 16B-aligned, 2-way banks */

typedef short bf8_t __attribute__((ext_vector_type(8)));
typedef float f4_t __attribute__((ext_vector_type(4)));

__device__ __forceinline__ unsigned short f2bfbits(float v) {
  __hip_bfloat16 h = __float2bfloat16(v);
  return *(unsigned short*)&h;
}
__device__ __forceinline__ float bfu_lo(unsigned int v) {
  unsigned int x = v << 16;
  return *(float*)&x;
}
__device__ __forceinline__ float bfu_hi(unsigned int v) {
  unsigned int x = v & 0xffff0000u;
  return *(float*)&x;
}
__device__ __forceinline__ float bf16f(unsigned short h) {
  unsigned int x = ((unsigned int)h) << 16;
  return *(float*)&x;
}

// async global->LDS 16B per lane; LDS dest is wave-uniform base + lane*16
__device__ __forceinline__ void gl_lds16(const void* g, void* l) {
  __builtin_amdgcn_global_load_lds(
      (const __attribute__((address_space(1))) unsigned int*)g,
      (__attribute__((address_space(3))) unsigned int*)l,
      16, 0, 0);
}

__device__ __forceinline__ void ld8f(const float* p, unsigned short* d) {
  const float4 a = ((const float4*)p)[0];
  const float4 b = ((const float4*)p)[1];
  d[0] = f2bfbits(a.x); d[1] = f2bfbits(a.y); d[2] = f2bfbits(a.z); d[3] = f2bfbits(a.w);
  d[4] = f2bfbits(b.x); d[5] = f2bfbits(b.y); d[6] = f2bfbits(b.z); d[7] = f2bfbits(b.w);
}

#define VMCNT(n) asm volatile("s_waitcnt vmcnt(" #n ")" ::: "memory")
#define LGKM0 asm volatile("s_waitcnt lgkmcnt(0)" ::: "memory")

// ---------------- dtype probe (1 = bf16 inputs, 0 = fp32 inputs) ----------------
__global__ void probe_kernel(const unsigned short* __restrict__ p, int* __restrict__ flag) {
  int lane = threadIdx.x;  // 64 lanes
  int sane = 0;
#pragma unroll
  for (int j = 0; j < 4; j++) {
    unsigned short lo = p[(lane * 4 + j) * 2];
    int e = (lo >> 7) & 0xFF;
    sane += (e <= 130) ? 1 : 0;
  }
  sane += __shfl_xor(sane, 1, 64);
  sane += __shfl_xor(sane, 2, 64);
  sane += __shfl_xor(sane, 4, 64);
  sane += __shfl_xor(sane, 8, 64);
  sane += __shfl_xor(sane, 16, 64);
  sane += __shfl_xor(sane, 32, 64);
  if (lane == 0) *flag = (sane >= 220) ? 1 : 0;
}

// ---------------- cast x fp32 -> bf16 (no-op when inputs already bf16) ----------------
__global__ __launch_bounds__(256) void cast_kernel(
    const int* __restrict__ flag, const float* __restrict__ x,
    unsigned short* __restrict__ xbf) {
  if (*flag == 1) return;
  int i = (blockIdx.x * 256 + threadIdx.x) * 8;
  unsigned short d[8];
  ld8f(x + i, d);
  *(uint4*)&xbf[i] = *(uint4*)d;
}

// ---------------- prep: canonicalize small weights to fp32 ----------------
#define PREP_TOT 78848
__global__ __launch_bounds__(256) void prep_kernel(
    const int* __restrict__ flag,
    const void* s0, const void* s1, const void* s2, const void* s3,
    const void* s4, const void* s5, const void* s6, const void* s7,
    float* __restrict__ out) {
  int i = blockIdx.x * 256 + threadIdx.x;
  if (i >= PREP_TOT) return;
  const void* src; int off;
  if      (i < 4096)   { src = s0; off = i; }
  else if (i < 5120)   { src = s1; off = i - 4096; }
  else if (i < 9216)   { src = s2; off = i - 5120; }
  else if (i < 10240)  { src = s3; off = i - 9216; }
  else if (i < 75776)  { src = s4; off = i - 10240; }
  else if (i < 76800)  { src = s5; off = i - 75776; }
  else if (i < 77824)  { src = s6; off = i - 76800; }
  else                 { src = s7; off = i - 77824; }
  float v = (*flag == 1) ? __bfloat162float(((const __hip_bfloat16*)src)[off])
                         : ((const float*)src)[off];
  out[i] = v;
}

// ---------------- transpose: Wt[n][k] bf16 <- W[k][n] (dtype by flag) ----------------
__global__ __launch_bounds__(256) void transpose_kernel(
    const int* __restrict__ flag, const void* __restrict__ W,
    unsigned short* __restrict__ Wt, int K, int N) {
  __shared__ unsigned short tile[32][33];
  int n0 = blockIdx.x * 32, k0 = blockIdx.y * 32;
  int c = threadIdx.x & 31, r8 = threadIdx.x >> 5;
  bool isbf = (*flag == 1);
#pragma unroll
  for (int p = 0; p < 4; p++) {
    int r = r8 + p * 8;
    unsigned short v;
    if (isbf) v = ((const unsigned short*)W)[(size_t)(k0 + r) * N + n0 + c];
    else      v = f2bfbits(((const float*)W)[(size_t)(k0 + r) * N + n0 + c]);
    tile[r][c] = v;
  }
  __syncthreads();
#pragma unroll
  for (int p = 0; p < 4; p++) {
    int r = r8 + p * 8;
    Wt[(size_t)(n0 + r) * K + k0 + c] = tile[c][r];
  }
}

// transpose W_xdbl [1024][96] -> Wxt [128][1024] bf16, rows 96..127 zero
__global__ __launch_bounds__(256) void transpose_pad_kernel(
    const int* __restrict__ flag, const void* __restrict__ W,
    unsigned short* __restrict__ Wt) {
  __shared__ unsigned short tile[32][33];
  int n0 = blockIdx.x * 32, k0 = blockIdx.y * 32;
  int c = threadIdx.x & 31, r8 = threadIdx.x >> 5;
  bool isbf = (*flag == 1);
#pragma unroll
  for (int p = 0; p < 4; p++) {
    int r = r8 + p * 8;
    unsigned short v = 0;
    if (n0 + c < RTOT) {
      if (isbf) v = ((const unsigned short*)W)[(size_t)(k0 + r) * RTOT + n0 + c];
      else      v = f2bfbits(((const float*)W)[(size_t)(k0 + r) * RTOT + n0 + c]);
    }
    tile[r][c] = v;
  }
  __syncthreads();
#pragma unroll
  for (int p = 0; p < 4; p++) {
    int r = r8 + p * 8;
    Wt[(size_t)(n0 + r) * DH + k0 + c] = tile[c][r];
  }
}

// ---------------- W_dt [64][1024] fp32 -> Wdtt [1024][192] bf16 (Whi|Whi|Wlo) ----------------
__global__ __launch_bounds__(256) void wdtt_kernel(
    const float* __restrict__ Wdt, unsigned short* __restrict__ Wdtt) {
  __shared__ unsigned short th[32][33], tl[32][33];
  int n0 = blockIdx.x * 32, k0 = blockIdx.y * 32;
  int c = threadIdx.x & 31, r8 = threadIdx.x >> 5;
#pragma unroll
  for (int p = 0; p < 4; p++) {
    int r = r8 + p * 8;
    float w = Wdt[(size_t)(k0 + r) * DH + n0 + c];
    unsigned short hi = f2bfbits(w);
    th[r][c] = hi;
    tl[r][c] = f2bfbits(w - bf16f(hi));
  }
  __syncthreads();
#pragma unroll
  for (int p = 0; p < 4; p++) {
    int r = r8 + p * 8;
    unsigned short hi = th[c][r], lo = tl[c][r];
    size_t base = (size_t)(n0 + r) * KD + k0 + c;
    Wdtt[base] = hi;
    Wdtt[base + 64] = hi;
    Wdtt[base + 128] = lo;
  }
}

// ---------------- MFMA GEMM (B^T): C[M,N] = A[M,K] @ Bt[N,K]^T (+bias) ----------------
// 256xBN tile, BK=32, 512 threads (8 waves 2Mx4N). 4-buffer LDS rotation,
// prefetch distance 3, counted vmcnt + raw s_barrier. Round-3 XCD swizzle.
// (unchanged from round 7)
template <int BN, bool OUT_BY_FLAG>
__global__ __launch_bounds__(512, 2) void gemm_bk32(
    const int* __restrict__ flag,
    const unsigned short* __restrict__ A1, const unsigned short* __restrict__ A0,
    const unsigned short* __restrict__ Bt,
    const float* __restrict__ bias, void* __restrict__ C,
    int N, int K) {
  extern __shared__ __align__(16) unsigned short lds[];
  constexpr int A_BUF = 256 * 32;       // shorts per A buffer (16KB)
  constexpr int B_BUF = BN * 32;        // shorts per B buffer
  constexpr int B_OFF = 4 * A_BUF;      // B region starts after 4 A buffers
  constexpr int NF = BN / 64;           // B frags per wave (4 or 2)
  constexpr int NB_LD = BN / 128;       // B gl_lds per thread per tile (2 or 1)

  const int flagv = *flag;
  const unsigned short* Ap = (flagv == 1) ? A1 : A0;

  const int tid = threadIdx.x;
  const int lane = tid & 63;
  const int wave = tid >> 6;
  const int quad = lane >> 4;
  const int l16 = lane & 15;
  const int wm = wave >> 2;
  const int wn = wave & 3;

  // XCD swizzle (grid = NB x 32 = 256 blocks, bijective)
  const int NB = gridDim.x, MB = gridDim.y;
  int L = blockIdx.y * NB + blockIdx.x;
  int xcd = L & 7;
  int w = L >> 3;
  int m_band = xcd * (MB >> 3) + (w / NB);
  int n_blk = w % NB;
  const int m0 = m_band * 256;
  const int n0 = n_blk * BN;

  const int NT = K >> 5;

  f4_t acc[8][NF] = {};

  auto stage = [&](int kt) {
    const int buf = kt & 3;
    const int k0 = kt * 32;
    unsigned short* Ad = lds + buf * A_BUF;
#pragma unroll
    for (int j = 0; j < 2; j++) {      // 1024 A chunks / 512 threads
      int ch = tid + j * 512;
      int mi = ch >> 2, s = ch & 3;
      int ki = s ^ ((mi >> 1) & 3);
      gl_lds16(Ap + (size_t)(m0 + mi) * K + k0 + ki * 8,
               Ad + (j * 512 + wave * 64) * 8);
    }
    unsigned short* Bd = lds + B_OFF + buf * B_BUF;
#pragma unroll
    for (int j = 0; j < NB_LD; j++) {  // BN*4 B chunks / 512 threads
      int ch = tid + j * 512;
      int ni = ch >> 2, s = ch & 3;
      int ki = s ^ ((ni >> 1) & 3);
      gl_lds16(Bt + (size_t)(n0 + ni) * K + k0 + ki * 8,
               Bd + (j * 512 + wave * 64) * 8);
    }
  };

  stage(0); stage(1); stage(2);

  for (int t = 0; t < NT; t++) {
    // counted waits: tile t's loads are the oldest outstanding set
    if (t + 2 < NT) {
      if constexpr (NF == 4) VMCNT(8); else VMCNT(6);
    } else if (t + 1 < NT) {
      if constexpr (NF == 4) VMCNT(4); else VMCNT(3);
    } else {
      VMCNT(0);
    }
    __builtin_amdgcn_s_barrier();      // B1: all waves' tile-t loads landed

    const unsigned short* Ac = lds + (t & 3) * A_BUF;
    const unsigned short* Bc = lds + B_OFF + (t & 3) * B_BUF;
    bf8_t af[8], bfr[NF];
#pragma unroll
    for (int ti = 0; ti < 8; ti++) {
      int r = wm * 128 + ti * 16 + l16;
      af[ti] = *(const bf8_t*)&Ac[(r * 4 + (quad ^ ((r >> 1) & 3))) * 8];
    }
#pragma unroll
    for (int tj = 0; tj < NF; tj++) {
      int rn = wn * (BN / 4) + tj * 16 + l16;
      bfr[tj] = *(const bf8_t*)&Bc[(rn * 4 + (quad ^ ((rn >> 1) & 3))) * 8];
    }
    if (t + 3 < NT) stage(t + 3);      // refill buf[(t+3)&3] = buf[(t-1)&3]

    LGKM0;
    __builtin_amdgcn_sched_barrier(0); // rule #18: pin MFMAs below the wait
    __builtin_amdgcn_s_setprio(1);
#pragma unroll
    for (int ti = 0; ti < 8; ti++)
#pragma unroll
      for (int tj = 0; tj < NF; tj++)
        acc[ti][tj] = __builtin_amdgcn_mfma_f32_16x16x32_bf16(
            af[ti], bfr[tj], acc[ti][tj], 0, 0, 0);
    __builtin_amdgcn_s_setprio(0);
    __builtin_amdgcn_s_barrier();      // B2: all waves done reading buf[t&3]
  }

  // epilogue: C/D layout col=lane&15, row=quad*4+reg (verified m89/m91)
#pragma unroll
  for (int ti = 0; ti < 8; ti++) {
#pragma unroll
    for (int tj = 0; tj < NF; tj++) {
      int col = n0 + wn * (BN / 4) + tj * 16 + l16;
      float bv = bias ? bias[col] : 0.f;
#pragma unroll
      for (int r = 0; r < 4; r++) {
        int row = m0 + wm * 128 + ti * 16 + quad * 4 + r;
        float v = acc[ti][tj][r] + bv;
        if constexpr (!OUT_BY_FLAG) {
          __builtin_nontemporal_store(f2bfbits(v),
              (unsigned short*)C + (size_t)row * N + col);
        } else {
          if (flagv == 1)
            __builtin_nontemporal_store(f2bfbits(v),
                (unsigned short*)C + (size_t)row * N + col);
          else
            __builtin_nontemporal_store(v, (float*)C + (size_t)row * N + col);
        }
      }
    }
  }
}

// ---------------- xdbl: xdbl[M,96] = xs_bf[M,1024] @ Wxt[96,1024]^T ----------------
// LDS-free, 256 blocks. Also emits the split-bf16 A-operand for the delta GEMM:
// Ad[m][0..63]=hi(dt_low), [64..127]=lo, [128..191]=hi  (pairs with Whi|Whi|Wlo).
// xdbl fp32 written only for cols 64..95 (B,C for the scan); cols 0..63 are dead.
__global__ __launch_bounds__(256) void xdbl_kernel(
    const unsigned short* __restrict__ A, const unsigned short* __restrict__ Bt,
    float* __restrict__ xdbl, unsigned short* __restrict__ Adelta) {
  const int tid = threadIdx.x;
  const int wave = tid >> 6;
  const int lane = tid & 63;
  const int quad = lane >> 4;
  const int l16 = lane & 15;
  const int m0 = blockIdx.x * 32 + (wave & 1) * 16;
  const int c0 = (wave >> 1) * 48;

  f4_t acc[3] = {};
  const unsigned short* Ar = A + (size_t)(m0 + l16) * DH + quad * 8;
  const unsigned short* B0 = Bt + (size_t)(c0 + l16) * DH + quad * 8;
  const unsigned short* B1 = Bt + (size_t)(c0 + 16 + l16) * DH + quad * 8;
  const unsigned short* B2 = Bt + (size_t)(c0 + 32 + l16) * DH + quad * 8;

#pragma unroll 4
  for (int k0 = 0; k0 < DH; k0 += 32) {
    bf8_t af = *(const bf8_t*)(Ar + k0);
    bf8_t b0 = *(const bf8_t*)(B0 + k0);
    bf8_t b1 = *(const bf8_t*)(B1 + k0);
    bf8_t b2 = *(const bf8_t*)(B2 + k0);
    acc[0] = __builtin_amdgcn_mfma_f32_16x16x32_bf16(af, b0, acc[0], 0, 0, 0);
    acc[1] = __builtin_amdgcn_mfma_f32_16x16x32_bf16(af, b1, acc[1], 0, 0, 0);
    acc[2] = __builtin_amdgcn_mfma_f32_16x16x32_bf16(af, b2, acc[2], 0, 0, 0);
  }

#pragma unroll
  for (int tj = 0; tj < 3; tj++) {
    int col = c0 + tj * 16 + l16;
#pragma unroll
    for (int r = 0; r < 4; r++) {
      int row = m0 + quad * 4 + r;
      float v = acc[tj][r];
      if (col < 64) {
        unsigned short hi = f2bfbits(v);
        unsigned short lo = f2bfbits(v - bf16f(hi));
        size_t base = (size_t)row * KD + col;
        Adelta[base] = hi;
        Adelta[base + 64] = lo;
        Adelta[base + 128] = hi;
      } else {
        xdbl[(size_t)row * RTOT + col] = v;
      }
    }
  }
}

// ---------------- delta via MFMA: dt = dt_low @ W_dt (split-bf16, fp32-exact) ----------
// du[m][d] = bf16(softplus(dt + 2*inv_dt)) | (xs_bf[m][d] << 16)
//
// ROUND-8 REWRITE: the old version was latency-bound (69.5us; MfmaUtil 1.6%,
// VALU 7.3%, HBM 8%, Occ 21%): 512 blocks = 2 waves/SIMD, and each ks step
// issued 8 DEPENDENT ~200cy global B loads feeding MFMAs with nothing to hide
// under. Now: 64-row tiles -> 1024 blocks (3 blocks/CU, LDS-capped); B slice
// (128 rows x 192) staged ONCE into LDS (rows padded to 200 shorts: 400B rows
// keep 16B alignment and spread l16 lanes 4 banks apart); all 6 A-fragments
// prefetched to registers. Inner loop = ds_read_b128 + MFMA only.
__global__ __launch_bounds__(256) void delta_mfma_kernel(
    const unsigned short* __restrict__ Ad,   // [M][192] hi|lo|hi
    const unsigned short* __restrict__ Bd,   // [1024][192] Whi|Whi|Wlo
    const float* __restrict__ inv_dt,
    const unsigned short* __restrict__ xs,
    unsigned int* __restrict__ du) {
  __shared__ __align__(16) unsigned short Bs[128 * KDP];  // 50KB
  const int tid = threadIdx.x;
  const int wave = tid >> 6;
  const int lane = tid & 63;
  const int quad = lane >> 4;
  const int l16 = lane & 15;
  const int m0 = blockIdx.x * 64 + wave * 16;
  const int n0 = blockIdx.y * 128;

  // stage B slice: 128 rows x 192 shorts = 3072 16B-chunks, 12 per thread
#pragma unroll
  for (int i = 0; i < 12; i++) {
    int ch = tid + i * 256;
    int row = ch / 24, cs = ch % 24;    // 24 chunks per 192-short row
    uint4 v = *(const uint4*)(Bd + (size_t)(n0 + row) * KD + cs * 8);
    *(uint4*)&Bs[row * KDP + cs * 8] = v;
  }

  // prefetch all 6 A fragments (L2-hot, 24 VGPRs)
  bf8_t a[6];
  const unsigned short* Ar = Ad + (size_t)(m0 + l16) * KD + quad * 8;
#pragma unroll
  for (int ks = 0; ks < 6; ks++) a[ks] = *(const bf8_t*)(Ar + ks * 32);

  __syncthreads();

  f4_t acc[8] = {};
#pragma unroll
  for (int ks = 0; ks < 6; ks++) {
#pragma unroll
    for (int nj = 0; nj < 8; nj++) {
      bf8_t b = *(const bf8_t*)&Bs[(nj * 16 + l16) * KDP + quad * 8 + ks * 32];
      acc[nj] = __builtin_amdgcn_mfma_f32_16x16x32_bf16(a[ks], b, acc[nj], 0, 0, 0);
    }
  }

#pragma unroll
  for (int nj = 0; nj < 8; nj++) {
    int col = n0 + nj * 16 + l16;
    float bias2 = 2.f * inv_dt[col];
#pragma unroll
    for (int r = 0; r < 4; r++) {
      int row = m0 + quad * 4 + r;
      float v = acc[nj][r] + bias2;
      float sp = (v > 0.f) ? (v + __logf(1.f + __expf(-v)))
                           : __logf(1.f + __expf(v));
      unsigned int lo = f2bfbits(sp);
      unsigned int hi = xs[(size_t)row * DH + col];
      du[(size_t)row * DH + col] = lo | (hi << 16);
    }
  }
}

// ---------------- depthwise conv (k=4, SAME: pad_low=1) + SiLU ----------------
// 4 timesteps per thread: 7 input rows for 4 outputs -> xz re-read 128MB -> 56MB.
__global__ __launch_bounds__(256) void conv_silu_kernel(
    const unsigned short* __restrict__ xz,
    const float* __restrict__ wx, const float* __restrict__ bx,
    const float* __restrict__ wz, const float* __restrict__ bz,
    unsigned short* __restrict__ xs_bf, unsigned short* __restrict__ cat) {
  int gid = blockIdx.x * 256 + threadIdx.x;  // (MROWS/4)*128 threads
  int cg = gid & 127;
  int c0 = cg * 8;
  int g = gid >> 7;
  int m0 = g * 4;                 // 4-row group (never straddles a sequence)
  int t0 = m0 & (LSEQ - 1);
  int mbase = m0 - t0;

  float wxr[4][8], wzr[4][8];
#pragma unroll
  for (int j = 0; j < 4; j++) {
    *(float4*)&wxr[j][0] = *(const float4*)&wx[j * DH + c0];
    *(float4*)&wxr[j][4] = *(const float4*)&wx[j * DH + c0 + 4];
    *(float4*)&wzr[j][0] = *(const float4*)&wz[j * DH + c0];
    *(float4*)&wzr[j][4] = *(const float4*)&wz[j * DH + c0 + 4];
  }

  float ax[4][8], az[4][8];
#pragma unroll
  for (int o = 0; o < 4; o++)
#pragma unroll
    for (int i = 0; i < 8; i++) { ax[o][i] = bx[c0 + i]; az[o][i] = bz[c0 + i]; }

#pragma unroll
  for (int rr = 0; rr < 7; rr++) {
    int tt = t0 - 1 + rr;
    if (tt < 0 || tt >= LSEQ) continue;
    size_t row = (size_t)(mbase + tt);
    uint4 vx = *(const uint4*)&xz[row * DI + c0];
    uint4 vz = *(const uint4*)&xz[row * DI + DH + c0];
    const unsigned int* px = (const unsigned int*)&vx;
    const unsigned int* pz = (const unsigned int*)&vz;
    float xv[8], zv[8];
#pragma unroll
    for (int q = 0; q < 4; q++) {
      xv[q * 2] = bfu_lo(px[q]); xv[q * 2 + 1] = bfu_hi(px[q]);
      zv[q * 2] = bfu_lo(pz[q]); zv[q * 2 + 1] = bfu_hi(pz[q]);
    }
#pragma unroll
    for (int o = 0; o < 4; o++) {
      int j = rr - o;             // tap index for output t0+o
      if (j < 0 || j > 3) continue;
#pragma unroll
      for (int i = 0; i < 8; i++) {
        ax[o][i] = fmaf(wxr[j][i], xv[i], ax[o][i]);
        az[o][i] = fmaf(wzr[j][i], zv[i], az[o][i]);
      }
    }
  }

#pragma unroll
  for (int o = 0; o < 4; o++) {
    unsigned short sx[8], sz[8];
#pragma unroll
    for (int i = 0; i < 8; i++) {
      float vx = ax[o][i] / (1.f + __expf(-ax[o][i]));
      float vz = az[o][i] / (1.f + __expf(-az[o][i]));
      sx[i] = f2bfbits(vx);
      sz[i] = f2bfbits(vz);
    }
    size_t m = (size_t)(m0 + o);
    *(uint4*)&xs_bf[m * DH + c0] = *(uint4*)sx;
    *(uint4*)&cat[m * DI + DH + c0] = *(uint4*)sz;
  }
}

// ---------------- chunked selective scan (packed du) ----------------
__global__ __launch_bounds__(256) void scan_pass1(
    const unsigned int* __restrict__ du, const float* __restrict__ xdbl,
    float* __restrict__ Echunks, float* __restrict__ hp) {
  const int tid = threadIdx.x;
  const int d = blockIdx.x * 256 + tid;
  const int c = blockIdx.y, b = blockIdx.z;
  const int row0 = b * LSEQ + c * CHUNK;
  __shared__ float sBC[CHUNK][32];  // [t][0..15]=B, [16..31]=C
#pragma unroll
  for (int i = 0; i < 2; i++) {
    int task = tid + i * 256;
    int r = task >> 3, seg = task & 7;
    *(float4*)&sBC[r][seg * 4] =
        *(const float4*)&xdbl[(size_t)(row0 + r) * RTOT + DTR + seg * 4];
  }
  __syncthreads();
  float h[16];
#pragma unroll
  for (int n = 0; n < 16; n++) h[n] = 0.f;
  float E = 1.f;
  for (int t = 0; t < CHUNK; t++) {
    unsigned int v = du[(size_t)(row0 + t) * DH + d];
    float dt = bfu_lo(v), ut = bfu_hi(v);
    float e = __expf(-dt);
    E *= e;
    float dv = dt * ut;
    float p = 1.f;
#pragma unroll
    for (int n = 0; n < 16; n++) {
      p *= e;
      h[n] = fmaf(p, h[n], dv * sBC[t][n]);
    }
  }
  Echunks[((size_t)c * B_SZ + b) * DH + d] = E;
#pragma unroll
  for (int n = 0; n < 16; n++)
    hp[(((size_t)c * B_SZ + b) * 16 + n) * DH + d] = h[n];
}

__global__ __launch_bounds__(256) void scan_pass2(
    const float* __restrict__ Echunks, const float* __restrict__ hp,
    float* __restrict__ hs) {
  int t = blockIdx.x * 256 + threadIdx.x;
  int d = t & 1023;
  int n = (t >> 10) & 15;
  int b = t >> 14;
  float h = 0.f;
  const int k0 = n + 1;
  for (int c = 0; c < NCH; c++) {
    float E = Echunks[((size_t)c * B_SZ + b) * DH + d];
    float a = 1.f, base = E;
    int k = k0;
#pragma unroll
    for (int i = 0; i < 5; i++) {
      if (k & 1) a *= base;
      base *= base;
      k >>= 1;
    }
    size_t idx = (((size_t)c * B_SZ + b) * 16 + n) * DH + d;
    hs[idx] = h;
    h = fmaf(a, h, hp[idx]);
  }
}

__global__ __launch_bounds__(256) void scan_pass3(
    const unsigned int* __restrict__ du, const float* __restrict__ xdbl,
    const float* __restrict__ hs, const float* __restrict__ Dvec,
    __hip_bfloat16* __restrict__ cat) {
  const int tid = threadIdx.x;
  const int d = blockIdx.x * 256 + tid;
  const int c = blockIdx.y, b = blockIdx.z;
  const int row0 = b * LSEQ + c * CHUNK;
  __shared__ float sBC[CHUNK][32];
#pragma unroll
  for (int i = 0; i < 2; i++) {
    int task = tid + i * 256;
    int r = task >> 3, seg = task & 7;
    *(float4*)&sBC[r][seg * 4] =
        *(const float4*)&xdbl[(size_t)(row0 + r) * RTOT + DTR + seg * 4];
  }
  __syncthreads();
  float h[16];
#pragma unroll
  for (int n = 0; n < 16; n++)
    h[n] = hs[(((size_t)c * B_SZ + b) * 16 + n) * DH + d];
  const float Dd = Dvec[d];
  for (int t = 0; t < CHUNK; t++) {
    unsigned int v = du[(size_t)(row0 + t) * DH + d];
    float dt = bfu_lo(v), ut = bfu_hi(v);
    float e = __expf(-dt);
    float dv = dt * ut;
    float p = 1.f, y = 0.f;
#pragma unroll
    for (int n = 0; n < 16; n++) {
      p *= e;
      h[n] = fmaf(p, h[n], dv * sBC[t][n]);
      y = fmaf(h[n], sBC[t][16 + n], y);
    }
    y = fmaf(ut, Dd, y);
    cat[(size_t)(row0 + t) * DI + d] = __float2bfloat16(y);
  }
}

extern "C" void kernel_launch(void* const* d_in, const int* in_sizes, int n_in,
                              void* d_out, int out_size, void* d_ws, size_t ws_size,
                              hipStream_t stream) {
  char* ws = (char*)d_ws;
  // layout (MB offsets):
  // [0,32): xz bf16 [8192][2048]; later du uint32 [8192][1024] (xz dead after conv)
  // [32,48): xs bf16 [8192][1024]
  // [48,64): xbf bf16 [8192][1024] (cast of x when inputs fp32)
  // [64,96): cat bf16 (y cols 0..1023, z cols 1024..2047)
  // [96,99): xdbl fp32 [8192][96]
  // [99,99.5): Echunks
  // [100,108): hp  — Wdtt bf16 [1024][192] first (lifetimes disjoint)
  // [108,116): hs — A_delta bf16 [8192][192] first (lifetimes disjoint)
  // [116,120): Wt_in bf16 | [120,124): Wt_out bf16 | [124,124.25): Wxt bf16
  // [125,+316KB): canonical fp32 weights | [126]: flag
  __hip_bfloat16* xz  = (__hip_bfloat16*)(ws);
  unsigned int* du    = (unsigned int*)(ws);
  __hip_bfloat16* xs  = (__hip_bfloat16*)(ws + ((size_t)32 << 20));
  unsigned short* xbf = (unsigned short*)(ws + ((size_t)48 << 20));
  __hip_bfloat16* cat = (__hip_bfloat16*)(ws + ((size_t)64 << 20));
  float* xdbl         = (float*)(ws + ((size_t)96 << 20));
  float* Echunks      = (float*)(ws + ((size_t)99 << 20));
  float* hp           = (float*)(ws + ((size_t)100 << 20));
  unsigned short* Wdtt = (unsigned short*)(ws + ((size_t)100 << 20));
  float* hs           = (float*)(ws + ((size_t)108 << 20));
  unsigned short* Adelta = (unsigned short*)(ws + ((size_t)108 << 20));
  unsigned short* Wt_in  = (unsigned short*)(ws + ((size_t)116 << 20));
  unsigned short* Wt_out = (unsigned short*)(ws + ((size_t)120 << 20));
  unsigned short* Wxt    = (unsigned short*)(ws + ((size_t)124 << 20));
  float* cw           = (float*)(ws + ((size_t)125 << 20));
  int* flag           = (int*)(ws + ((size_t)126 << 20));

  const float* conv_xwf = cw + 0;
  const float* conv_xbf = cw + 4096;
  const float* conv_zwf = cw + 5120;
  const float* conv_zbf = cw + 9216;
  const float* Wdtf     = cw + 10240;
  const float* inv_dtf  = cw + 75776;
  const float* Df       = cw + 76800;
  const float* b_outf   = cw + 77824;

  // opt-in to >64KB dynamic LDS
  (void)hipFuncSetAttribute(reinterpret_cast<const void*>(&gemm_bk32<256, false>),
                            hipFuncAttributeMaxDynamicSharedMemorySize, 131072);
  (void)hipFuncSetAttribute(reinterpret_cast<const void*>(&gemm_bk32<128, true>),
                            hipFuncAttributeMaxDynamicSharedMemorySize, 98304);

  probe_kernel<<<1, 64, 0, stream>>>((const unsigned short*)d_in[0], flag);
  cast_kernel<<<4096, 256, 0, stream>>>(flag, (const float*)d_in[0], xbf);
  prep_kernel<<<(PREP_TOT + 255) / 256, 256, 0, stream>>>(
      flag, d_in[2], d_in[3], d_in[4], d_in[5], d_in[7], d_in[8], d_in[9],
      d_in[11], cw);
  transpose_kernel<<<dim3(DI / 32, DM / 32), 256, 0, stream>>>(
      flag, d_in[1], Wt_in, DM, DI);
  transpose_kernel<<<dim3(DM / 32, DI / 32), 256, 0, stream>>>(
      flag, d_in[10], Wt_out, DI, DM);
  transpose_pad_kernel<<<dim3(4, DH / 32), 256, 0, stream>>>(flag, d_in[6], Wxt);
  wdtt_kernel<<<dim3(DH / 32, 2), 256, 0, stream>>>(Wdtf, Wdtt);

  // 1) xz = x @ W_in  (M=8192,N=2048,K=1024), tile 256x256, round-3 swizzle
  gemm_bk32<256, false><<<dim3(DI / 256, MROWS / 256), 512, 131072, stream>>>(
      flag, (const unsigned short*)d_in[0], xbf, Wt_in,
      (const float*)nullptr, xz, DI, DM);
  // 2) conv + silu -> xs bf16, cat z-half (4 timesteps/thread)
  conv_silu_kernel<<<(MROWS / 4) * 128 / 256, 256, 0, stream>>>(
      (const unsigned short*)xz, conv_xwf, conv_xbf, conv_zwf, conv_zbf,
      (unsigned short*)xs, (unsigned short*)cat);
  // 3) x_dbl = xs @ W_xdbl (LDS-free MFMA); also emits split-bf16 A for delta
  xdbl_kernel<<<MROWS / 32, 256, 0, stream>>>(
      (const unsigned short*)xs, Wxt, xdbl, Adelta);
  // 4) delta via MFMA: 1024 blocks, B in LDS, A prefetched (was 69.5us)
  delta_mfma_kernel<<<dim3(MROWS / 64, DH / 128), 256, 0, stream>>>(
      Adelta, Wdtt, inv_dtf, (const unsigned short*)xs, du);
  // 5) chunked scan
  scan_pass1<<<dim3(4, NCH, B_SZ), 256, 0, stream>>>(du, xdbl, Echunks, hp);
  scan_pass2<<<256, 256, 0, stream>>>(Echunks, hp, hs);
  scan_pass3<<<dim3(4, NCH, B_SZ), 256, 0, stream>>>(du, xdbl, hs, Df, cat);
  // 6) out = cat @ W_out + b_out  (M=8192,N=1024,K=2048), tile 256x128,
  //    round-3 swizzle
  gemm_bk32<128, true><<<dim3(DM / 128, MROWS / 256), 512, 98304, stream>>>(
      flag, (const unsigned short*)cat, (const unsigned short*)cat, Wt_out,
      b_outf, d_out, DM, DI);
}

// Round 9
// 344.384 us; speedup vs baseline: 1.0455x; 1.0455x over previous
//
#include <hip/hip_runtime.h>
#include <hip/hip_bf16.h>
#include <math.h>

#define B_SZ 4
#define LSEQ 2048
#define DM 1024
#define DI 2048
#define DH 1024
#define DS 16
#define DTR 64
#define RTOT 96
#define MROWS (B_SZ * LSEQ) /* 8192 */

// scan chunking
#define NCH 32
#define CHUNK 64 /* LSEQ / NCH */

// delta split-bf16 GEMM K (hi|lo|hi vs Whi|Whi|Wlo)
#define KD 192
#define KDP 200 /* padded LDS row (shorts): 400B = 16B-aligned, 2-way banks */

typedef short bf8_t __attribute__((ext_vector_type(8)));
typedef float f4_t __attribute__((ext_vector_type(4)));

__device__ __forceinline__ unsigned short f2bfbits(float v) {
  __hip_bfloat16 h = __float2bfloat16(v);
  return *(unsigned short*)&h;
}
__device__ __forceinline__ float bfu_lo(unsigned int v) {
  unsigned int x = v << 16;
  return *(float*)&x;
}
__device__ __forceinline__ float bfu_hi(unsigned int v) {
  unsigned int x = v & 0xffff0000u;
  return *(float*)&x;
}
__device__ __forceinline__ float bf16f(unsigned short h) {
  unsigned int x = ((unsigned int)h) << 16;
  return *(float*)&x;
}

// async global->LDS 16B per lane; LDS dest is wave-uniform base + lane*16
__device__ __forceinline__ void gl_lds16(const void* g, void* l) {
  __builtin_amdgcn_global_load_lds(
      (const __attribute__((address_space(1))) unsigned int*)g,
      (__attribute__((address_space(3))) unsigned int*)l,
      16, 0, 0);
}

__device__ __forceinline__ void ld8f(const float* p, unsigned short* d) {
  const float4 a = ((const float4*)p)[0];
  const float4 b = ((const float4*)p)[1];
  d[0] = f2bfbits(a.x); d[1] = f2bfbits(a.y); d[2] = f2bfbits(a.z); d[3] = f2bfbits(a.w);
  d[4] = f2bfbits(b.x); d[5] = f2bfbits(b.y); d[6] = f2bfbits(b.z); d[7] = f2bfbits(b.w);
}

// e^(n+1) for n=0..15, log-depth ladder (replaces 16-deep serial p*=e chain)
__device__ __forceinline__ void pow_ladder(float e, float* pw) {
  float e2 = e * e, e4 = e2 * e2, e8 = e4 * e4;
  float e3 = e2 * e, e5 = e4 * e, e6 = e4 * e2, e7 = e4 * e3;
  pw[0] = e;        pw[1] = e2;       pw[2] = e3;       pw[3] = e4;
  pw[4] = e5;       pw[5] = e6;       pw[6] = e7;       pw[7] = e8;
  pw[8] = e8 * e;   pw[9] = e8 * e2;  pw[10] = e8 * e3; pw[11] = e8 * e4;
  pw[12] = e8 * e5; pw[13] = e8 * e6; pw[14] = e8 * e7; pw[15] = e8 * e8;
}

#define VMCNT(n) asm volatile("s_waitcnt vmcnt(" #n ")" ::: "memory")
#define LGKM0 asm volatile("s_waitcnt lgkmcnt(0)" ::: "memory")

// ---------------- dtype probe (1 = bf16 inputs, 0 = fp32 inputs) ----------------
__global__ void probe_kernel(const unsigned short* __restrict__ p, int* __restrict__ flag) {
  int lane = threadIdx.x;  // 64 lanes
  int sane = 0;
#pragma unroll
  for (int j = 0; j < 4; j++) {
    unsigned short lo = p[(lane * 4 + j) * 2];
    int e = (lo >> 7) & 0xFF;
    sane += (e <= 130) ? 1 : 0;
  }
  sane += __shfl_xor(sane, 1, 64);
  sane += __shfl_xor(sane, 2, 64);
  sane += __shfl_xor(sane, 4, 64);
  sane += __shfl_xor(sane, 8, 64);
  sane += __shfl_xor(sane, 16, 64);
  sane += __shfl_xor(sane, 32, 64);
  if (lane == 0) *flag = (sane >= 220) ? 1 : 0;
}

// ---------------- cast x fp32 -> bf16 (no-op when inputs already bf16) ----------------
__global__ __launch_bounds__(256) void cast_kernel(
    const int* __restrict__ flag, const float* __restrict__ x,
    unsigned short* __restrict__ xbf) {
  if (*flag == 1) return;
  int i = (blockIdx.x * 256 + threadIdx.x) * 8;
  unsigned short d[8];
  ld8f(x + i, d);
  *(uint4*)&xbf[i] = *(uint4*)d;
}

// ---------------- prep: canonicalize small weights to fp32 ----------------
#define PREP_TOT 78848
__global__ __launch_bounds__(256) void prep_kernel(
    const int* __restrict__ flag,
    const void* s0, const void* s1, const void* s2, const void* s3,
    const void* s4, const void* s5, const void* s6, const void* s7,
    float* __restrict__ out) {
  int i = blockIdx.x * 256 + threadIdx.x;
  if (i >= PREP_TOT) return;
  const void* src; int off;
  if      (i < 4096)   { src = s0; off = i; }
  else if (i < 5120)   { src = s1; off = i - 4096; }
  else if (i < 9216)   { src = s2; off = i - 5120; }
  else if (i < 10240)  { src = s3; off = i - 9216; }
  else if (i < 75776)  { src = s4; off = i - 10240; }
  else if (i < 76800)  { src = s5; off = i - 75776; }
  else if (i < 77824)  { src = s6; off = i - 76800; }
  else                 { src = s7; off = i - 77824; }
  float v = (*flag == 1) ? __bfloat162float(((const __hip_bfloat16*)src)[off])
                         : ((const float*)src)[off];
  out[i] = v;
}

// ---------------- transpose: Wt[n][k] bf16 <- W[k][n] (dtype by flag) ----------------
__global__ __launch_bounds__(256) void transpose_kernel(
    const int* __restrict__ flag, const void* __restrict__ W,
    unsigned short* __restrict__ Wt, int K, int N) {
  __shared__ unsigned short tile[32][33];
  int n0 = blockIdx.x * 32, k0 = blockIdx.y * 32;
  int c = threadIdx.x & 31, r8 = threadIdx.x >> 5;
  bool isbf = (*flag == 1);
#pragma unroll
  for (int p = 0; p < 4; p++) {
    int r = r8 + p * 8;
    unsigned short v;
    if (isbf) v = ((const unsigned short*)W)[(size_t)(k0 + r) * N + n0 + c];
    else      v = f2bfbits(((const float*)W)[(size_t)(k0 + r) * N + n0 + c]);
    tile[r][c] = v;
  }
  __syncthreads();
#pragma unroll
  for (int p = 0; p < 4; p++) {
    int r = r8 + p * 8;
    Wt[(size_t)(n0 + r) * K + k0 + c] = tile[c][r];
  }
}

// transpose W_xdbl [1024][96] -> Wxt [128][1024] bf16, rows 96..127 zero
__global__ __launch_bounds__(256) void transpose_pad_kernel(
    const int* __restrict__ flag, const void* __restrict__ W,
    unsigned short* __restrict__ Wt) {
  __shared__ unsigned short tile[32][33];
  int n0 = blockIdx.x * 32, k0 = blockIdx.y * 32;
  int c = threadIdx.x & 31, r8 = threadIdx.x >> 5;
  bool isbf = (*flag == 1);
#pragma unroll
  for (int p = 0; p < 4; p++) {
    int r = r8 + p * 8;
    unsigned short v = 0;
    if (n0 + c < RTOT) {
      if (isbf) v = ((const unsigned short*)W)[(size_t)(k0 + r) * RTOT + n0 + c];
      else      v = f2bfbits(((const float*)W)[(size_t)(k0 + r) * RTOT + n0 + c]);
    }
    tile[r][c] = v;
  }
  __syncthreads();
#pragma unroll
  for (int p = 0; p < 4; p++) {
    int r = r8 + p * 8;
    Wt[(size_t)(n0 + r) * DH + k0 + c] = tile[c][r];
  }
}

// ---------------- W_dt [64][1024] fp32 -> Wdtt [1024][192] bf16 (Whi|Whi|Wlo) ----------------
__global__ __launch_bounds__(256) void wdtt_kernel(
    const float* __restrict__ Wdt, unsigned short* __restrict__ Wdtt) {
  __shared__ unsigned short th[32][33], tl[32][33];
  int n0 = blockIdx.x * 32, k0 = blockIdx.y * 32;
  int c = threadIdx.x & 31, r8 = threadIdx.x >> 5;
#pragma unroll
  for (int p = 0; p < 4; p++) {
    int r = r8 + p * 8;
    float w = Wdt[(size_t)(k0 + r) * DH + n0 + c];
    unsigned short hi = f2bfbits(w);
    th[r][c] = hi;
    tl[r][c] = f2bfbits(w - bf16f(hi));
  }
  __syncthreads();
#pragma unroll
  for (int p = 0; p < 4; p++) {
    int r = r8 + p * 8;
    unsigned short hi = th[c][r], lo = tl[c][r];
    size_t base = (size_t)(n0 + r) * KD + k0 + c;
    Wdtt[base] = hi;
    Wdtt[base + 64] = hi;
    Wdtt[base + 128] = lo;
  }
}

// ---------------- MFMA GEMM (B^T): C[M,N] = A[M,K] @ Bt[N,K]^T (+bias) ----------------
// 256xBN tile, BK=32, 512 threads (8 waves 2Mx4N). 4-buffer LDS rotation,
// prefetch distance 3, counted vmcnt + raw s_barrier. Round-3 XCD swizzle.
// (unchanged)
template <int BN, bool OUT_BY_FLAG>
__global__ __launch_bounds__(512, 2) void gemm_bk32(
    const int* __restrict__ flag,
    const unsigned short* __restrict__ A1, const unsigned short* __restrict__ A0,
    const unsigned short* __restrict__ Bt,
    const float* __restrict__ bias, void* __restrict__ C,
    int N, int K) {
  extern __shared__ __align__(16) unsigned short lds[];
  constexpr int A_BUF = 256 * 32;       // shorts per A buffer (16KB)
  constexpr int B_BUF = BN * 32;        // shorts per B buffer
  constexpr int B_OFF = 4 * A_BUF;      // B region starts after 4 A buffers
  constexpr int NF = BN / 64;           // B frags per wave (4 or 2)
  constexpr int NB_LD = BN / 128;       // B gl_lds per thread per tile (2 or 1)

  const int flagv = *flag;
  const unsigned short* Ap = (flagv == 1) ? A1 : A0;

  const int tid = threadIdx.x;
  const int lane = tid & 63;
  const int wave = tid >> 6;
  const int quad = lane >> 4;
  const int l16 = lane & 15;
  const int wm = wave >> 2;
  const int wn = wave & 3;

  // XCD swizzle (grid = NB x 32 = 256 blocks, bijective)
  const int NB = gridDim.x, MB = gridDim.y;
  int L = blockIdx.y * NB + blockIdx.x;
  int xcd = L & 7;
  int w = L >> 3;
  int m_band = xcd * (MB >> 3) + (w / NB);
  int n_blk = w % NB;
  const int m0 = m_band * 256;
  const int n0 = n_blk * BN;

  const int NT = K >> 5;

  f4_t acc[8][NF] = {};

  auto stage = [&](int kt) {
    const int buf = kt & 3;
    const int k0 = kt * 32;
    unsigned short* Ad = lds + buf * A_BUF;
#pragma unroll
    for (int j = 0; j < 2; j++) {      // 1024 A chunks / 512 threads
      int ch = tid + j * 512;
      int mi = ch >> 2, s = ch & 3;
      int ki = s ^ ((mi >> 1) & 3);
      gl_lds16(Ap + (size_t)(m0 + mi) * K + k0 + ki * 8,
               Ad + (j * 512 + wave * 64) * 8);
    }
    unsigned short* Bd = lds + B_OFF + buf * B_BUF;
#pragma unroll
    for (int j = 0; j < NB_LD; j++) {  // BN*4 B chunks / 512 threads
      int ch = tid + j * 512;
      int ni = ch >> 2, s = ch & 3;
      int ki = s ^ ((ni >> 1) & 3);
      gl_lds16(Bt + (size_t)(n0 + ni) * K + k0 + ki * 8,
               Bd + (j * 512 + wave * 64) * 8);
    }
  };

  stage(0); stage(1); stage(2);

  for (int t = 0; t < NT; t++) {
    // counted waits: tile t's loads are the oldest outstanding set
    if (t + 2 < NT) {
      if constexpr (NF == 4) VMCNT(8); else VMCNT(6);
    } else if (t + 1 < NT) {
      if constexpr (NF == 4) VMCNT(4); else VMCNT(3);
    } else {
      VMCNT(0);
    }
    __builtin_amdgcn_s_barrier();      // B1: all waves' tile-t loads landed

    const unsigned short* Ac = lds + (t & 3) * A_BUF;
    const unsigned short* Bc = lds + B_OFF + (t & 3) * B_BUF;
    bf8_t af[8], bfr[NF];
#pragma unroll
    for (int ti = 0; ti < 8; ti++) {
      int r = wm * 128 + ti * 16 + l16;
      af[ti] = *(const bf8_t*)&Ac[(r * 4 + (quad ^ ((r >> 1) & 3))) * 8];
    }
#pragma unroll
    for (int tj = 0; tj < NF; tj++) {
      int rn = wn * (BN / 4) + tj * 16 + l16;
      bfr[tj] = *(const bf8_t*)&Bc[(rn * 4 + (quad ^ ((rn >> 1) & 3))) * 8];
    }
    if (t + 3 < NT) stage(t + 3);      // refill buf[(t+3)&3] = buf[(t-1)&3]

    LGKM0;
    __builtin_amdgcn_sched_barrier(0); // rule #18: pin MFMAs below the wait
    __builtin_amdgcn_s_setprio(1);
#pragma unroll
    for (int ti = 0; ti < 8; ti++)
#pragma unroll
      for (int tj = 0; tj < NF; tj++)
        acc[ti][tj] = __builtin_amdgcn_mfma_f32_16x16x32_bf16(
            af[ti], bfr[tj], acc[ti][tj], 0, 0, 0);
    __builtin_amdgcn_s_setprio(0);
    __builtin_amdgcn_s_barrier();      // B2: all waves done reading buf[t&3]
  }

  // epilogue: C/D layout col=lane&15, row=quad*4+reg (verified m89/m91)
#pragma unroll
  for (int ti = 0; ti < 8; ti++) {
#pragma unroll
    for (int tj = 0; tj < NF; tj++) {
      int col = n0 + wn * (BN / 4) + tj * 16 + l16;
      float bv = bias ? bias[col] : 0.f;
#pragma unroll
      for (int r = 0; r < 4; r++) {
        int row = m0 + wm * 128 + ti * 16 + quad * 4 + r;
        float v = acc[ti][tj][r] + bv;
        if constexpr (!OUT_BY_FLAG) {
          __builtin_nontemporal_store(f2bfbits(v),
              (unsigned short*)C + (size_t)row * N + col);
        } else {
          if (flagv == 1)
            __builtin_nontemporal_store(f2bfbits(v),
                (unsigned short*)C + (size_t)row * N + col);
          else
            __builtin_nontemporal_store(v, (float*)C + (size_t)row * N + col);
        }
      }
    }
  }
}

// ---------------- xdbl: xdbl[M,96] = xs_bf[M,1024] @ Wxt[96,1024]^T ----------------
// LDS-free, 256 blocks. Also emits the split-bf16 A-operand for the delta GEMM.
__global__ __launch_bounds__(256) void xdbl_kernel(
    const unsigned short* __restrict__ A, const unsigned short* __restrict__ Bt,
    float* __restrict__ xdbl, unsigned short* __restrict__ Adelta) {
  const int tid = threadIdx.x;
  const int wave = tid >> 6;
  const int lane = tid & 63;
  const int quad = lane >> 4;
  const int l16 = lane & 15;
  const int m0 = blockIdx.x * 32 + (wave & 1) * 16;
  const int c0 = (wave >> 1) * 48;

  f4_t acc[3] = {};
  const unsigned short* Ar = A + (size_t)(m0 + l16) * DH + quad * 8;
  const unsigned short* B0 = Bt + (size_t)(c0 + l16) * DH + quad * 8;
  const unsigned short* B1 = Bt + (size_t)(c0 + 16 + l16) * DH + quad * 8;
  const unsigned short* B2 = Bt + (size_t)(c0 + 32 + l16) * DH + quad * 8;

#pragma unroll 4
  for (int k0 = 0; k0 < DH; k0 += 32) {
    bf8_t af = *(const bf8_t*)(Ar + k0);
    bf8_t b0 = *(const bf8_t*)(B0 + k0);
    bf8_t b1 = *(const bf8_t*)(B1 + k0);
    bf8_t b2 = *(const bf8_t*)(B2 + k0);
    acc[0] = __builtin_amdgcn_mfma_f32_16x16x32_bf16(af, b0, acc[0], 0, 0, 0);
    acc[1] = __builtin_amdgcn_mfma_f32_16x16x32_bf16(af, b1, acc[1], 0, 0, 0);
    acc[2] = __builtin_amdgcn_mfma_f32_16x16x32_bf16(af, b2, acc[2], 0, 0, 0);
  }

#pragma unroll
  for (int tj = 0; tj < 3; tj++) {
    int col = c0 + tj * 16 + l16;
#pragma unroll
    for (int r = 0; r < 4; r++) {
      int row = m0 + quad * 4 + r;
      float v = acc[tj][r];
      if (col < 64) {
        unsigned short hi = f2bfbits(v);
        unsigned short lo = f2bfbits(v - bf16f(hi));
        size_t base = (size_t)row * KD + col;
        Adelta[base] = hi;
        Adelta[base + 64] = lo;
        Adelta[base + 128] = hi;
      } else {
        xdbl[(size_t)row * RTOT + col] = v;
      }
    }
  }
}

// ---------------- delta via MFMA (round-8 version: B in LDS, A prefetched) ----------
__global__ __launch_bounds__(256) void delta_mfma_kernel(
    const unsigned short* __restrict__ Ad,   // [M][192] hi|lo|hi
    const unsigned short* __restrict__ Bd,   // [1024][192] Whi|Whi|Wlo
    const float* __restrict__ inv_dt,
    const unsigned short* __restrict__ xs,
    unsigned int* __restrict__ du) {
  __shared__ __align__(16) unsigned short Bs[128 * KDP];  // 50KB
  const int tid = threadIdx.x;
  const int wave = tid >> 6;
  const int lane = tid & 63;
  const int quad = lane >> 4;
  const int l16 = lane & 15;
  const int m0 = blockIdx.x * 64 + wave * 16;
  const int n0 = blockIdx.y * 128;

  // stage B slice: 128 rows x 192 shorts = 3072 16B-chunks, 12 per thread
#pragma unroll
  for (int i = 0; i < 12; i++) {
    int ch = tid + i * 256;
    int row = ch / 24, cs = ch % 24;    // 24 chunks per 192-short row
    uint4 v = *(const uint4*)(Bd + (size_t)(n0 + row) * KD + cs * 8);
    *(uint4*)&Bs[row * KDP + cs * 8] = v;
  }

  // prefetch all 6 A fragments (L2-hot, 24 VGPRs)
  bf8_t a[6];
  const unsigned short* Ar = Ad + (size_t)(m0 + l16) * KD + quad * 8;
#pragma unroll
  for (int ks = 0; ks < 6; ks++) a[ks] = *(const bf8_t*)(Ar + ks * 32);

  __syncthreads();

  f4_t acc[8] = {};
#pragma unroll
  for (int ks = 0; ks < 6; ks++) {
#pragma unroll
    for (int nj = 0; nj < 8; nj++) {
      bf8_t b = *(const bf8_t*)&Bs[(nj * 16 + l16) * KDP + quad * 8 + ks * 32];
      acc[nj] = __builtin_amdgcn_mfma_f32_16x16x32_bf16(a[ks], b, acc[nj], 0, 0, 0);
    }
  }

#pragma unroll
  for (int nj = 0; nj < 8; nj++) {
    int col = n0 + nj * 16 + l16;
    float bias2 = 2.f * inv_dt[col];
#pragma unroll
    for (int r = 0; r < 4; r++) {
      int row = m0 + quad * 4 + r;
      float v = acc[nj][r] + bias2;
      float sp = (v > 0.f) ? (v + __logf(1.f + __expf(-v)))
                           : __logf(1.f + __expf(v));
      unsigned int lo = f2bfbits(sp);
      unsigned int hi = xs[(size_t)row * DH + col];
      du[(size_t)row * DH + col] = lo | (hi << 16);
    }
  }
}

// ---------------- depthwise conv (k=4, SAME: pad_low=1) + SiLU ----------------
__global__ __launch_bounds__(256) void conv_silu_kernel(
    const unsigned short* __restrict__ xz,
    const float* __restrict__ wx, const float* __restrict__ bx,
    const float* __restrict__ wz, const float* __restrict__ bz,
    unsigned short* __restrict__ xs_bf, unsigned short* __restrict__ cat) {
  int gid = blockIdx.x * 256 + threadIdx.x;  // (MROWS/4)*128 threads
  int cg = gid & 127;
  int c0 = cg * 8;
  int g = gid >> 7;
  int m0 = g * 4;                 // 4-row group (never straddles a sequence)
  int t0 = m0 & (LSEQ - 1);
  int mbase = m0 - t0;

  float wxr[4][8], wzr[4][8];
#pragma unroll
  for (int j = 0; j < 4; j++) {
    *(float4*)&wxr[j][0] = *(const float4*)&wx[j * DH + c0];
    *(float4*)&wxr[j][4] = *(const float4*)&wx[j * DH + c0 + 4];
    *(float4*)&wzr[j][0] = *(const float4*)&wz[j * DH + c0];
    *(float4*)&wzr[j][4] = *(const float4*)&wz[j * DH + c0 + 4];
  }

  float ax[4][8], az[4][8];
#pragma unroll
  for (int o = 0; o < 4; o++)
#pragma unroll
    for (int i = 0; i < 8; i++) { ax[o][i] = bx[c0 + i]; az[o][i] = bz[c0 + i]; }

#pragma unroll
  for (int rr = 0; rr < 7; rr++) {
    int tt = t0 - 1 + rr;
    if (tt < 0 || tt >= LSEQ) continue;
    size_t row = (size_t)(mbase + tt);
    uint4 vx = *(const uint4*)&xz[row * DI + c0];
    uint4 vz = *(const uint4*)&xz[row * DI + DH + c0];
    const unsigned int* px = (const unsigned int*)&vx;
    const unsigned int* pz = (const unsigned int*)&vz;
    float xv[8], zv[8];
#pragma unroll
    for (int q = 0; q < 4; q++) {
      xv[q * 2] = bfu_lo(px[q]); xv[q * 2 + 1] = bfu_hi(px[q]);
      zv[q * 2] = bfu_lo(pz[q]); zv[q * 2 + 1] = bfu_hi(pz[q]);
    }
#pragma unroll
    for (int o = 0; o < 4; o++) {
      int j = rr - o;             // tap index for output t0+o
      if (j < 0 || j > 3) continue;
#pragma unroll
      for (int i = 0; i < 8; i++) {
        ax[o][i] = fmaf(wxr[j][i], xv[i], ax[o][i]);
        az[o][i] = fmaf(wzr[j][i], zv[i], az[o][i]);
      }
    }
  }

#pragma unroll
  for (int o = 0; o < 4; o++) {
    unsigned short sx[8], sz[8];
#pragma unroll
    for (int i = 0; i < 8; i++) {
      float vx = ax[o][i] / (1.f + __expf(-ax[o][i]));
      float vz = az[o][i] / (1.f + __expf(-az[o][i]));
      sx[i] = f2bfbits(vx);
      sz[i] = f2bfbits(vz);
    }
    size_t m = (size_t)(m0 + o);
    *(uint4*)&xs_bf[m * DH + c0] = *(uint4*)sx;
    *(uint4*)&cat[m * DI + DH + c0] = *(uint4*)sz;
  }
}

// ---------------- chunked selective scan (packed du) ----------------
// ROUND-9 REWRITE of pass1/pass3: both were latency-bound like old delta
// (one thread per (d,chunk) scan; 64 DEPENDENT global du loads in the t-loop;
// 16-deep serial p*=e multiply chain per t; scan3 also a 16-deep serial y-FMA
// chain). Now: (a) the block's du slice (64t x 256d = 64KB) is staged into
// LDS via gl_lds16 up front -> t-loop reads are ~6cy LDS broadcasts the
// compiler pipelines; (b) p-chain replaced by log-depth power ladder
// (pow_ladder, depth ~4); (c) scan3's y-sum uses 4 parallel accumulators.
// Dynamic LDS 72KB (64KB du + 8KB sBC), 2 blocks/CU (same occupancy as before).
__global__ __launch_bounds__(256) void scan_pass1(
    const unsigned int* __restrict__ du, const float* __restrict__ xdbl,
    float* __restrict__ Echunks, float* __restrict__ hp) {
  extern __shared__ __align__(16) unsigned int sm1[];
  unsigned int* sDU = sm1;                    // [CHUNK][256] = 64KB
  float* sBC = (float*)(sm1 + CHUNK * 256);   // [CHUNK][32] = 8KB
  const int tid = threadIdx.x;
  const int wave = tid >> 6;
  const int d0 = blockIdx.x * 256;
  const int c = blockIdx.y, b = blockIdx.z;
  const int row0 = b * LSEQ + c * CHUNK;

  // stage du slice: 64 rows x 1KB = 4096 16B-chunks, 16 per thread
  const unsigned int* src = du + (size_t)row0 * DH + d0;
#pragma unroll
  for (int i = 0; i < 16; i++) {
    int ch = tid + i * 256;
    int r = ch >> 6, cs = ch & 63;
    gl_lds16(src + (size_t)r * DH + cs * 4, sDU + (i * 256 + wave * 64) * 4);
  }
#pragma unroll
  for (int i = 0; i < 2; i++) {
    int task = tid + i * 256;
    int r = task >> 3, seg = task & 7;
    *(float4*)&sBC[r * 32 + seg * 4] =
        *(const float4*)&xdbl[(size_t)(row0 + r) * RTOT + DTR + seg * 4];
  }
  __syncthreads();

  float h[16];
#pragma unroll
  for (int n = 0; n < 16; n++) h[n] = 0.f;
  float E = 1.f;
  for (int t = 0; t < CHUNK; t++) {
    unsigned int v = sDU[t * 256 + tid];
    float dt = bfu_lo(v), ut = bfu_hi(v);
    float e = __expf(-dt);
    E *= e;
    float dv = dt * ut;
    float pw[16];
    pow_ladder(e, pw);
#pragma unroll
    for (int n = 0; n < 16; n++)
      h[n] = fmaf(pw[n], h[n], dv * sBC[t * 32 + n]);
  }
  const int d = d0 + tid;
  Echunks[((size_t)c * B_SZ + b) * DH + d] = E;
#pragma unroll
  for (int n = 0; n < 16; n++)
    hp[(((size_t)c * B_SZ + b) * 16 + n) * DH + d] = h[n];
}

__global__ __launch_bounds__(256) void scan_pass2(
    const float* __restrict__ Echunks, const float* __restrict__ hp,
    float* __restrict__ hs) {
  int t = blockIdx.x * 256 + threadIdx.x;
  int d = t & 1023;
  int n = (t >> 10) & 15;
  int b = t >> 14;
  float h = 0.f;
  const int k0 = n + 1;
  for (int c = 0; c < NCH; c++) {
    float E = Echunks[((size_t)c * B_SZ + b) * DH + d];
    float a = 1.f, base = E;
    int k = k0;
#pragma unroll
    for (int i = 0; i < 5; i++) {
      if (k & 1) a *= base;
      base *= base;
      k >>= 1;
    }
    size_t idx = (((size_t)c * B_SZ + b) * 16 + n) * DH + d;
    hs[idx] = h;
    h = fmaf(a, h, hp[idx]);
  }
}

__global__ __launch_bounds__(256) void scan_pass3(
    const unsigned int* __restrict__ du, const float* __restrict__ xdbl,
    const float* __restrict__ hs, const float* __restrict__ Dvec,
    __hip_bfloat16* __restrict__ cat) {
  extern __shared__ __align__(16) unsigned int sm1[];
  unsigned int* sDU = sm1;                    // [CHUNK][256] = 64KB
  float* sBC = (float*)(sm1 + CHUNK * 256);   // [CHUNK][32] = 8KB
  const int tid = threadIdx.x;
  const int wave = tid >> 6;
  const int d0 = blockIdx.x * 256;
  const int c = blockIdx.y, b = blockIdx.z;
  const int row0 = b * LSEQ + c * CHUNK;

  const unsigned int* src = du + (size_t)row0 * DH + d0;
#pragma unroll
  for (int i = 0; i < 16; i++) {
    int ch = tid + i * 256;
    int r = ch >> 6, cs = ch & 63;
    gl_lds16(src + (size_t)r * DH + cs * 4, sDU + (i * 256 + wave * 64) * 4);
  }
#pragma unroll
  for (int i = 0; i < 2; i++) {
    int task = tid + i * 256;
    int r = task >> 3, seg = task & 7;
    *(float4*)&sBC[r * 32 + seg * 4] =
        *(const float4*)&xdbl[(size_t)(row0 + r) * RTOT + DTR + seg * 4];
  }

  const int d = d0 + tid;
  float h[16];
#pragma unroll
  for (int n = 0; n < 16; n++)
    h[n] = hs[(((size_t)c * B_SZ + b) * 16 + n) * DH + d];
  const float Dd = Dvec[d];
  __syncthreads();

  for (int t = 0; t < CHUNK; t++) {
    unsigned int v = sDU[t * 256 + tid];
    float dt = bfu_lo(v), ut = bfu_hi(v);
    float e = __expf(-dt);
    float dv = dt * ut;
    float pw[16];
    pow_ladder(e, pw);
    float y0 = 0.f, y1 = 0.f, y2 = 0.f, y3 = 0.f;
#pragma unroll
    for (int n = 0; n < 16; n += 4) {
      h[n]     = fmaf(pw[n],     h[n],     dv * sBC[t * 32 + n]);
      h[n + 1] = fmaf(pw[n + 1], h[n + 1], dv * sBC[t * 32 + n + 1]);
      h[n + 2] = fmaf(pw[n + 2], h[n + 2], dv * sBC[t * 32 + n + 2]);
      h[n + 3] = fmaf(pw[n + 3], h[n + 3], dv * sBC[t * 32 + n + 3]);
      y0 = fmaf(h[n],     sBC[t * 32 + 16 + n],     y0);
      y1 = fmaf(h[n + 1], sBC[t * 32 + 16 + n + 1], y1);
      y2 = fmaf(h[n + 2], sBC[t * 32 + 16 + n + 2], y2);
      y3 = fmaf(h[n + 3], sBC[t * 32 + 16 + n + 3], y3);
    }
    float y = (y0 + y1) + (y2 + y3);
    y = fmaf(ut, Dd, y);
    cat[(size_t)(row0 + t) * DI + d] = __float2bfloat16(y);
  }
}

extern "C" void kernel_launch(void* const* d_in, const int* in_sizes, int n_in,
                              void* d_out, int out_size, void* d_ws, size_t ws_size,
                              hipStream_t stream) {
  char* ws = (char*)d_ws;
  // layout (MB offsets):
  // [0,32): xz bf16 [8192][2048]; later du uint32 [8192][1024] (xz dead after conv)
  // [32,48): xs bf16 [8192][1024]
  // [48,64): xbf bf16 [8192][1024] (cast of x when inputs fp32)
  // [64,96): cat bf16 (y cols 0..1023, z cols 1024..2047)
  // [96,99): xdbl fp32 [8192][96]
  // [99,99.5): Echunks
  // [100,108): hp  — Wdtt bf16 [1024][192] first (lifetimes disjoint)
  // [108,116): hs — A_delta bf16 [8192][192] first (lifetimes disjoint)
  // [116,120): Wt_in bf16 | [120,124): Wt_out bf16 | [124,124.25): Wxt bf16
  // [125,+316KB): canonical fp32 weights | [126]: flag
  __hip_bfloat16* xz  = (__hip_bfloat16*)(ws);
  unsigned int* du    = (unsigned int*)(ws);
  __hip_bfloat16* xs  = (__hip_bfloat16*)(ws + ((size_t)32 << 20));
  unsigned short* xbf = (unsigned short*)(ws + ((size_t)48 << 20));
  __hip_bfloat16* cat = (__hip_bfloat16*)(ws + ((size_t)64 << 20));
  float* xdbl         = (float*)(ws + ((size_t)96 << 20));
  float* Echunks      = (float*)(ws + ((size_t)99 << 20));
  float* hp           = (float*)(ws + ((size_t)100 << 20));
  unsigned short* Wdtt = (unsigned short*)(ws + ((size_t)100 << 20));
  float* hs           = (float*)(ws + ((size_t)108 << 20));
  unsigned short* Adelta = (unsigned short*)(ws + ((size_t)108 << 20));
  unsigned short* Wt_in  = (unsigned short*)(ws + ((size_t)116 << 20));
  unsigned short* Wt_out = (unsigned short*)(ws + ((size_t)120 << 20));
  unsigned short* Wxt    = (unsigned short*)(ws + ((size_t)124 << 20));
  float* cw           = (float*)(ws + ((size_t)125 << 20));
  int* flag           = (int*)(ws + ((size_t)126 << 20));

  const float* conv_xwf = cw + 0;
  const float* conv_xbf = cw + 4096;
  const float* conv_zwf = cw + 5120;
  const float* conv_zbf = cw + 9216;
  const float* Wdtf     = cw + 10240;
  const float* inv_dtf  = cw + 75776;
  const float* Df       = cw + 76800;
  const float* b_outf   = cw + 77824;

  // opt-in to >64KB dynamic LDS
  (void)hipFuncSetAttribute(reinterpret_cast<const void*>(&gemm_bk32<256, false>),
                            hipFuncAttributeMaxDynamicSharedMemorySize, 131072);
  (void)hipFuncSetAttribute(reinterpret_cast<const void*>(&gemm_bk32<128, true>),
                            hipFuncAttributeMaxDynamicSharedMemorySize, 98304);
  (void)hipFuncSetAttribute(reinterpret_cast<const void*>(&scan_pass1),
                            hipFuncAttributeMaxDynamicSharedMemorySize, 73728);
  (void)hipFuncSetAttribute(reinterpret_cast<const void*>(&scan_pass3),
                            hipFuncAttributeMaxDynamicSharedMemorySize, 73728);

  probe_kernel<<<1, 64, 0, stream>>>((const unsigned short*)d_in[0], flag);
  cast_kernel<<<4096, 256, 0, stream>>>(flag, (const float*)d_in[0], xbf);
  prep_kernel<<<(PREP_TOT + 255) / 256, 256, 0, stream>>>(
      flag, d_in[2], d_in[3], d_in[4], d_in[5], d_in[7], d_in[8], d_in[9],
      d_in[11], cw);
  transpose_kernel<<<dim3(DI / 32, DM / 32), 256, 0, stream>>>(
      flag, d_in[1], Wt_in, DM, DI);
  transpose_kernel<<<dim3(DM / 32, DI / 32), 256, 0, stream>>>(
      flag, d_in[10], Wt_out, DI, DM);
  transpose_pad_kernel<<<dim3(4, DH / 32), 256, 0, stream>>>(flag, d_in[6], Wxt);
  wdtt_kernel<<<dim3(DH / 32, 2), 256, 0, stream>>>(Wdtf, Wdtt);

  // 1) xz = x @ W_in  (M=8192,N=2048,K=1024), tile 256x256, round-3 swizzle
  gemm_bk32<256, false><<<dim3(DI / 256, MROWS / 256), 512, 131072, stream>>>(
      flag, (const unsigned short*)d_in[0], xbf, Wt_in,
      (const float*)nullptr, xz, DI, DM);
  // 2) conv + silu -> xs bf16, cat z-half (4 timesteps/thread)
  conv_silu_kernel<<<(MROWS / 4) * 128 / 256, 256, 0, stream>>>(
      (const unsigned short*)xz, conv_xwf, conv_xbf, conv_zwf, conv_zbf,
      (unsigned short*)xs, (unsigned short*)cat);
  // 3) x_dbl = xs @ W_xdbl (LDS-free MFMA); also emits split-bf16 A for delta
  xdbl_kernel<<<MROWS / 32, 256, 0, stream>>>(
      (const unsigned short*)xs, Wxt, xdbl, Adelta);
  // 4) delta via MFMA: 1024 blocks, B in LDS, A prefetched
  delta_mfma_kernel<<<dim3(MROWS / 64, DH / 128), 256, 0, stream>>>(
      Adelta, Wdtt, inv_dtf, (const unsigned short*)xs, du);
  // 5) chunked scan (pass1/pass3: LDS-staged du + power-ladder)
  scan_pass1<<<dim3(4, NCH, B_SZ), 256, 73728, stream>>>(du, xdbl, Echunks, hp);
  scan_pass2<<<256, 256, 0, stream>>>(Echunks, hp, hs);
  scan_pass3<<<dim3(4, NCH, B_SZ), 256, 73728, stream>>>(du, xdbl, hs, Df, cat);
  // 6) out = cat @ W_out + b_out  (M=8192,N=1024,K=2048), tile 256x128,
  //    round-3 swizzle
  gemm_bk32<128, true><<<dim3(DM / 128, MROWS / 256), 512, 98304, stream>>>(
      flag, (const unsigned short*)cat, (const unsigned short*)cat, Wt_out,
      b_outf, d_out, DM, DI);
}